// Round 10
// baseline (91.288 us; speedup 1.0000x reference)
//
#include <hip/hip_runtime.h>
#include <hip/hip_bf16.h>
#include <stdint.h>

#define N_ROWS 8192
#define M_ROWS 16384
#define CDIM 128
#define MSPLIT 16
#define NT 16      // B tiles per block: 16 x 64 rows = 1024 rows per msplit
#define BTR 64     // B rows per tile (16 KB)
#define TILE_U16 (BTR * CDIM)

typedef unsigned short u16;
typedef __attribute__((ext_vector_type(2))) unsigned short u16x2;
typedef __attribute__((ext_vector_type(8))) short bf16x8;
typedef __attribute__((ext_vector_type(16))) float f32x16;

static __device__ __forceinline__ u16 f2bf(float x) {
  union { float f; uint32_t u; } v; v.f = x;
  uint32_t u = v.u;
  uint32_t r = u + 0x7FFFu + ((u >> 16) & 1u);  // RTNE
  return (u16)(r >> 16);
}
static __device__ __forceinline__ float bf2f(u16 b) {
  union { uint32_t u; float f; } v; v.u = ((uint32_t)b) << 16;
  return v.f;
}

#define GLOAD_LDS(gsrc, ldst)                                                  \
  __builtin_amdgcn_global_load_lds(                                            \
      (const __attribute__((address_space(1))) uint32_t*)(gsrc),               \
      (__attribute__((address_space(3))) uint32_t*)(ldst), 16, 0, 0)

// One wave per row: fp32 -> bf16 copies, row sum-of-squares of the
// bf16-rounded values (fp32 accum). Memory rows store mh = -0.5*||m||^2
// (seeds the MFMA accumulator in the gemm). Inits the min-d2 buffer.
__global__ __launch_bounds__(256) void prep_kernel(
    const float* __restrict__ f, const float* __restrict__ m,
    u16* __restrict__ fb, u16* __restrict__ mb,
    float* __restrict__ f2, float* __restrict__ mh, int* __restrict__ mind2)
{
  const int row = blockIdx.x * 4 + (threadIdx.x >> 6);
  const int lane = threadIdx.x & 63;
  const bool isF = row < N_ROWS;
  const float* src = isF ? (f + (size_t)row * CDIM)
                         : (m + (size_t)(row - N_ROWS) * CDIM);
  float2 v = *(const float2*)(src + lane * 2);
  u16 b0 = f2bf(v.x), b1 = f2bf(v.y);
  float x0 = bf2f(b0), x1 = bf2f(b1);
  float s = x0 * x0 + x1 * x1;
#pragma unroll
  for (int mask = 1; mask < 64; mask <<= 1)
    s += __shfl_xor(s, mask, 64);
  u16x2 bb = {b0, b1};
  if (isF) {
    *(u16x2*)(fb + (size_t)row * CDIM + lane * 2) = bb;
    if (lane == 0) { f2[row] = s; mind2[row] = 0x7F7FFFFF; }  // +FLT_MAX bits
  } else {
    const int r = row - N_ROWS;
    *(u16x2*)(mb + (size_t)r * CDIM + lane * 2) = bb;
    if (lane == 0) mh[r] = -0.5f * s;
  }
}

// 256 thr = 4 waves (2 wm x 2 wn); block tile 128 A-rows x 64 B-rows/tile;
// wave tile 64A x 32B via mfma_f32_32x32x16_bf16. A in registers (full
// K=128). B triple-buffered 16 KB tiles, 2-tile lookahead, ONE s_barrier +
// counted vmcnt(4) per tile (queue never drains; vmcnt(4) = newest tile's 4
// chunks remain -> next-read tile provably landed; bg ds_reads stay
// PRE-barrier so the only cross-wave overwrite hazard is one-barrier-
// separated -- round-9-proven placement). acc seeded with mh=-m2/2 so
// min d2 = f2 - 2*max(acc).  LDS = 52 KB -> 3 blocks/CU (12 waves): the
// round-9 counters showed ~50% dead stall at 1 block/CU; independent
// resident blocks absorb it (m114 regime).
// grid (16 msplit, 64 ntile): linear%16 spreads msplit over XCDs; per-XCD
// working set 2 x 256 KB B-slices, L2-resident.
__global__ __launch_bounds__(256, 3) void gemm_min_kernel(
    const u16* __restrict__ fb, const u16* __restrict__ mb,
    const float* __restrict__ f2, const float* __restrict__ mh,
    int* __restrict__ mind2)
{
  __shared__ __align__(16) u16 bts[3 * TILE_U16];  // 48 KB
  __shared__ __align__(16) float mhl[1024];        // 4 KB
  const int tid = threadIdx.x;
  const int msplit = blockIdx.x;
  const int nbase = blockIdx.y * 128;

  const int lane = tid & 63;
  const int w = tid >> 6;    // 0..3
  const int wm = w >> 1;     // 0..1 : 64-row A group
  const int wn = w & 1;      // 0..1 : 32-row B group
  const int l31 = lane & 31;
  const int l5 = lane >> 5;          // 0/1: k-half
  const int chSw = lane & 15;        // chunk-index XOR (row&15 == lane&15)

  // Per-thread staging offsets (4 x 16B chunks per 16 KB tile).
  int srcOffs[4], dstOffs[4];
#pragma unroll
  for (int c = 0; c < 4; ++c) {
    const int t16 = c * 256 + tid;
    srcOffs[c] = (t16 ^ ((t16 >> 4) & 15)) * 8;  // u16 units
    dstOffs[c] = t16 * 8;
  }

  // ---- Prologue: stage A (32 KB -> buf0+buf1) + mh slice ----
  {
    const u16* srcA = fb + (size_t)nbase * CDIM;
#pragma unroll
    for (int c = 0; c < 8; ++c) {
      const int t16 = c * 256 + tid;
      const int so = (t16 ^ ((t16 >> 4) & 15)) * 8;
      GLOAD_LDS(srcA + so, bts + t16 * 8);
    }
    GLOAD_LDS(mh + msplit * 1024 + tid * 4, mhl + tid * 4);
  }
  asm volatile("s_waitcnt vmcnt(0)" ::: "memory");
  __builtin_amdgcn_s_barrier();

  // A fragments -> registers (64 VGPRs). row = wm*64 + mi*32 + l31;
  // chunk = (ks*2 + l5) ^ (row&15), row&15 == lane&15 here.
  bf16x8 af[2][8];  // [mi][ks]
#pragma unroll
  for (int mi = 0; mi < 2; ++mi)
#pragma unroll
    for (int ks = 0; ks < 8; ++ks) {
      const int row = wm * 64 + mi * 32 + l31;
      af[mi][ks] = *(const bf16x8*)&bts[row * CDIM + (((ks * 2 + l5) ^ chSw) * 8)];
    }
  __syncthreads();  // all waves done reading A before buffers are reused

  // Stage tiles 0 and 1 into buffers 0 and 1.
  const u16* mbase_ptr = mb + (size_t)(msplit * 1024) * CDIM;
#pragma unroll
  for (int tt = 0; tt < 2; ++tt)
#pragma unroll
    for (int c = 0; c < 4; ++c)
      GLOAD_LDS(mbase_ptr + (size_t)tt * TILE_U16 + srcOffs[c],
                bts + tt * TILE_U16 + dstOffs[c]);
  asm volatile("s_waitcnt vmcnt(4)" ::: "memory");  // tile 0 landed
  __builtin_amdgcn_s_barrier();

  float tmax[2][16];
#pragma unroll
  for (int mi = 0; mi < 2; ++mi)
#pragma unroll
    for (int r = 0; r < 16; ++r) tmax[mi][r] = -3.0e38f;

  f32x16 acc[2];
  const int browL = wn * 32 + l31;   // B-row within tile
  int cur = 0;

  for (int t = 0; t < NT; ++t) {
    const u16* bt = bts + cur * TILE_U16;
    int stg = cur + 2; if (stg >= 3) stg -= 3;
    u16* stgbuf = bts + stg * TILE_U16;
    const u16* srcT2 = mbase_ptr + (size_t)((t + 2) & (NT - 1)) * TILE_U16;

    // Fold previous tile's results, then reseed acc with -m2/2.
    if (t) {
#pragma unroll
      for (int mi = 0; mi < 2; ++mi)
#pragma unroll
        for (int r = 0; r < 16; ++r)
          tmax[mi][r] = fmaxf(tmax[mi][r], acc[mi][r]);
    }
    const float mhv = mhl[t * BTR + browL];
#pragma unroll
    for (int mi = 0; mi < 2; ++mi)
#pragma unroll
      for (int r = 0; r < 16; ++r) acc[mi][r] = mhv;

    // This tile's B fragments (pre-barrier, round-9-proven placement).
    bf16x8 bg[8];
    {
      const u16* btrow = bt + browL * CDIM;
#pragma unroll
      for (int ks = 0; ks < 8; ++ks)
        bg[ks] = *(const bf16x8*)&btrow[((ks * 2 + l5) ^ chSw) * 8];
    }
    // Stage tile t+2 (4 chunks; lands ~2 windows from now).
#pragma unroll
    for (int c = 0; c < 4; ++c)
      GLOAD_LDS(srcT2 + srcOffs[c], stgbuf + dstOffs[c]);

    // Wait tile t+1's chunks (issued one window ago); t+2's stay in flight.
    asm volatile("s_waitcnt vmcnt(4)" ::: "memory");
    __builtin_amdgcn_s_barrier();

    __builtin_amdgcn_s_setprio(1);
#pragma unroll
    for (int ks = 0; ks < 8; ++ks)
#pragma unroll
      for (int mi = 0; mi < 2; ++mi)
        acc[mi] = __builtin_amdgcn_mfma_f32_32x32x16_bf16(
            af[mi][ks], bg[ks], acc[mi], 0, 0, 0);
    __builtin_amdgcn_s_setprio(0);

    cur += 1; if (cur >= 3) cur -= 3;
  }

  // Fold the last tile.
#pragma unroll
  for (int mi = 0; mi < 2; ++mi)
#pragma unroll
    for (int r = 0; r < 16; ++r)
      tmax[mi][r] = fmaxf(tmax[mi][r], acc[mi][r]);

  // Reduce across the 32 lanes (l31) holding a row's B-columns.
#pragma unroll
  for (int mi = 0; mi < 2; ++mi)
#pragma unroll
    for (int r = 0; r < 16; ++r) {
      float tv = tmax[mi][r];
      tv = fmaxf(tv, __shfl_xor(tv, 1, 64));
      tv = fmaxf(tv, __shfl_xor(tv, 2, 64));
      tv = fmaxf(tv, __shfl_xor(tv, 4, 64));
      tv = fmaxf(tv, __shfl_xor(tv, 8, 64));
      tv = fmaxf(tv, __shfl_xor(tv, 16, 64));
      tmax[mi][r] = tv;
    }
  if (l31 == 0) {  // lanes 0 and 32 (l5 = 0/1)
#pragma unroll
    for (int mi = 0; mi < 2; ++mi)
#pragma unroll
      for (int r = 0; r < 16; ++r) {
        // C/D: row = (r&3) + 8*(r>>2) + 4*l5 within the 32-row fragment.
        const int row = nbase + wm * 64 + mi * 32 + (r & 3) + 8 * (r >> 2) + 4 * l5;
        const float d2 = fmaxf(fmaf(-2.0f, tmax[mi][r], f2[row]), 0.0f);
        atomicMin(&mind2[row], __float_as_int(d2));
      }
  }
}

__global__ __launch_bounds__(256) void finalize_kernel(
    const int* __restrict__ mind2, float* __restrict__ out)
{
  const int i = blockIdx.x * 256 + threadIdx.x;
  out[i] = sqrtf(fmaxf(__int_as_float(mind2[i]), 0.0f));
}

extern "C" void kernel_launch(void* const* d_in, const int* in_sizes, int n_in,
                              void* d_out, int out_size, void* d_ws, size_t ws_size,
                              hipStream_t stream) {
  const float* f = (const float*)d_in[0];  // features  [8192,1,1,128] fp32
  const float* m = (const float*)d_in[1];  // patch_mem [1,16384,1,128] fp32

  char* ws = (char*)d_ws;
  u16*  fb    = (u16*)(ws);                                   // 2 MB
  u16*  mb    = (u16*)(ws + (2u << 20));                      // 4 MB
  float* f2   = (float*)(ws + (2u << 20) + (4u << 20));       // 32 KB
  float* mh   = (float*)(ws + (2u << 20) + (4u << 20) + (32u << 10));  // 64 KB
  int*  mind2 = (int*)(ws + (2u << 20) + (4u << 20) + (96u << 10));    // 32 KB

  hipLaunchKernelGGL(prep_kernel, dim3((N_ROWS + M_ROWS) / 4), dim3(256), 0, stream,
                     f, m, fb, mb, f2, mh, mind2);
  hipLaunchKernelGGL(gemm_min_kernel, dim3(MSPLIT, N_ROWS / 128), dim3(256), 0, stream,
                     fb, mb, f2, mh, mind2);
  hipLaunchKernelGGL(finalize_kernel, dim3(N_ROWS / 256), dim3(256), 0, stream,
                     mind2, (float*)d_out);
}

// Round 11
// 83.917 us; speedup vs baseline: 1.0878x; 1.0878x over previous
//
#include <hip/hip_runtime.h>
#include <hip/hip_bf16.h>
#include <stdint.h>

#define N_ROWS 8192
#define M_ROWS 16384
#define CDIM 128
#define MSPLIT 16      // B slices
#define SLICE_ROWS 1024
#define NT 32          // 32-row B tiles per slice

typedef unsigned short u16;
typedef __attribute__((ext_vector_type(2))) unsigned short u16x2;
typedef __attribute__((ext_vector_type(8))) short bf16x8;
typedef __attribute__((ext_vector_type(16))) float f32x16;

static __device__ __forceinline__ u16 f2bf(float x) {
  union { float f; uint32_t u; } v; v.f = x;
  uint32_t u = v.u;
  uint32_t r = u + 0x7FFFu + ((u >> 16) & 1u);  // RTNE
  return (u16)(r >> 16);
}
static __device__ __forceinline__ float bf2f(u16 b) {
  union { uint32_t u; float f; } v; v.u = ((uint32_t)b) << 16;
  return v.f;
}

// One wave per row: fp32 -> bf16 copies, row sum-of-squares of the
// bf16-rounded values (fp32 accum). Memory rows store mh = -0.5*||m||^2
// (seeds the MFMA accumulator in the gemm). Inits the min-d2 buffer.
__global__ __launch_bounds__(256) void prep_kernel(
    const float* __restrict__ f, const float* __restrict__ m,
    u16* __restrict__ fb, u16* __restrict__ mb,
    float* __restrict__ f2, float* __restrict__ mh, int* __restrict__ mind2)
{
  const int row = blockIdx.x * 4 + (threadIdx.x >> 6);
  const int lane = threadIdx.x & 63;
  const bool isF = row < N_ROWS;
  const float* src = isF ? (f + (size_t)row * CDIM)
                         : (m + (size_t)(row - N_ROWS) * CDIM);
  float2 v = *(const float2*)(src + lane * 2);
  u16 b0 = f2bf(v.x), b1 = f2bf(v.y);
  float x0 = bf2f(b0), x1 = bf2f(b1);
  float s = x0 * x0 + x1 * x1;
#pragma unroll
  for (int mask = 1; mask < 64; mask <<= 1)
    s += __shfl_xor(s, mask, 64);
  u16x2 bb = {b0, b1};
  if (isF) {
    *(u16x2*)(fb + (size_t)row * CDIM + lane * 2) = bb;
    if (lane == 0) { f2[row] = s; mind2[row] = 0x7F7FFFFF; }  // +FLT_MAX bits
  } else {
    const int r = row - N_ROWS;
    *(u16x2*)(mb + (size_t)r * CDIM + lane * 2) = bb;
    if (lane == 0) mh[r] = -0.5f * s;
  }
}

// ZERO-LDS, ZERO-BARRIER register GEMM (round-10 post-mortem: 6 LDS-staged
// schedule variants all barrier-convoy-bound at 13-16% MfmaUtil).
// Block = 4 independent waves; wave tile 64A x 32B via mfma_f32_32x32x16_bf16.
// A (64 rows x K=128) lives in af[2][8] (64 VGPR) loaded once from global.
// B streams global->VGPR: per 32-row tile, 8 x 16B/lane loads (fully packed),
// double-buffered (bgA/bgB) one tile ahead; double accumulators (accA/accB)
// let the fold-VALU of tile t overlap MFMA of t+1. All 4 waves read the SAME
// B tile sequence -> L1 sharing cuts L2 traffic ~4x (amp 8192/256=32 ->
// ~128 MB L2 total). acc seeded with mh=-m2/2 (C/D col==l31 for all regs ->
// one scalar/lane/tile), so min d2 = f2 - 2*max(acc).
// grid (16 msplit, 32 abase) = 512 blocks = 2/CU exactly; linear%8 pins
// msplit pairs per XCD (B working set 512 KB/XCD, L2-resident).
__global__ __launch_bounds__(256, 2) void gemm_min_kernel(
    const u16* __restrict__ fb, const u16* __restrict__ mb,
    const float* __restrict__ f2, const float* __restrict__ mh,
    int* __restrict__ mind2)
{
  const int tid = threadIdx.x;
  const int lane = tid & 63;
  const int w = tid >> 6;          // 0..3 : 64-row A group
  const int l31 = lane & 31;
  const int l5 = lane >> 5;        // 0/1 : k-half
  const int arow = blockIdx.y * 256 + w * 64 + l31;
  const size_t mslice = (size_t)blockIdx.x * SLICE_ROWS;

  // A fragments -> registers (64 VGPR), loaded once.
  bf16x8 af[2][8];  // [mi][ks]
#pragma unroll
  for (int mi = 0; mi < 2; ++mi)
#pragma unroll
    for (int ks = 0; ks < 8; ++ks)
      af[mi][ks] = *(const bf16x8*)&fb[(size_t)(arow + mi * 32) * CDIM
                                       + ks * 16 + l5 * 8];

  // Per-lane B base: row (mslice + l31), k-offset l5*8.
  const u16* bp = mb + (mslice + l31) * CDIM + l5 * 8;
  const float* mhp = mh + mslice + l31;

  bf16x8 bgA[8], bgB[8];
  float mhA, mhB;
#pragma unroll
  for (int ks = 0; ks < 8; ++ks)
    bgA[ks] = *(const bf16x8*)&bp[ks * 16];  // tile 0
  mhA = mhp[0];

  float tmax[2][16];
#pragma unroll
  for (int mi = 0; mi < 2; ++mi)
#pragma unroll
    for (int r = 0; r < 16; ++r) tmax[mi][r] = -3.0e38f;

  f32x16 accA[2], accB[2];
#pragma unroll
  for (int mi = 0; mi < 2; ++mi)
#pragma unroll
    for (int r = 0; r < 16; ++r) accB[mi][r] = -3.0e38f;  // first fold no-op

  for (int t = 0; t < NT; t += 2) {
    // Prefetch tile t+1 into bgB.
    {
      const u16* bp1 = bp + (size_t)(t + 1) * 32 * CDIM;
#pragma unroll
      for (int ks = 0; ks < 8; ++ks)
        bgB[ks] = *(const bf16x8*)&bp1[ks * 16];
      mhB = mhp[(t + 1) * 32];
    }
    // Seed accA with -m2/2, compute tile t; fold tile t-1 (accB) meanwhile.
#pragma unroll
    for (int mi = 0; mi < 2; ++mi)
#pragma unroll
      for (int r = 0; r < 16; ++r) accA[mi][r] = mhA;
#pragma unroll
    for (int ks = 0; ks < 8; ++ks)
#pragma unroll
      for (int mi = 0; mi < 2; ++mi)
        accA[mi] = __builtin_amdgcn_mfma_f32_32x32x16_bf16(
            af[mi][ks], bgA[ks], accA[mi], 0, 0, 0);
#pragma unroll
    for (int mi = 0; mi < 2; ++mi)
#pragma unroll
      for (int r = 0; r < 16; ++r)
        tmax[mi][r] = fmaxf(tmax[mi][r], accB[mi][r]);

    // Prefetch tile t+2 into bgA (wraps harmlessly at the end).
    {
      const u16* bp2 = bp + (size_t)((t + 2) & (NT - 1)) * 32 * CDIM;
#pragma unroll
      for (int ks = 0; ks < 8; ++ks)
        bgA[ks] = *(const bf16x8*)&bp2[ks * 16];
      mhA = mhp[((t + 2) & (NT - 1)) * 32];
    }
    // Seed accB, compute tile t+1; fold tile t (accA) meanwhile.
#pragma unroll
    for (int mi = 0; mi < 2; ++mi)
#pragma unroll
      for (int r = 0; r < 16; ++r) accB[mi][r] = mhB;
#pragma unroll
    for (int ks = 0; ks < 8; ++ks)
#pragma unroll
      for (int mi = 0; mi < 2; ++mi)
        accB[mi] = __builtin_amdgcn_mfma_f32_32x32x16_bf16(
            af[mi][ks], bgB[ks], accB[mi], 0, 0, 0);
#pragma unroll
    for (int mi = 0; mi < 2; ++mi)
#pragma unroll
      for (int r = 0; r < 16; ++r)
        tmax[mi][r] = fmaxf(tmax[mi][r], accA[mi][r]);
  }
  // Fold the last odd tile (accB of t=31).
#pragma unroll
  for (int mi = 0; mi < 2; ++mi)
#pragma unroll
    for (int r = 0; r < 16; ++r)
      tmax[mi][r] = fmaxf(tmax[mi][r], accB[mi][r]);

  // Reduce across the 32 lanes (l31) holding a row's B-columns.
#pragma unroll
  for (int mi = 0; mi < 2; ++mi)
#pragma unroll
    for (int r = 0; r < 16; ++r) {
      float tv = tmax[mi][r];
      tv = fmaxf(tv, __shfl_xor(tv, 1, 64));
      tv = fmaxf(tv, __shfl_xor(tv, 2, 64));
      tv = fmaxf(tv, __shfl_xor(tv, 4, 64));
      tv = fmaxf(tv, __shfl_xor(tv, 8, 64));
      tv = fmaxf(tv, __shfl_xor(tv, 16, 64));
      tmax[mi][r] = tv;
    }
  if (l31 == 0) {  // lanes 0 and 32 (l5 = 0/1)
#pragma unroll
    for (int mi = 0; mi < 2; ++mi)
#pragma unroll
      for (int r = 0; r < 16; ++r) {
        // C/D: row = (r&3) + 8*(r>>2) + 4*l5 within the 32-row fragment.
        const int row = blockIdx.y * 256 + w * 64 + mi * 32
                        + (r & 3) + 8 * (r >> 2) + 4 * l5;
        const float d2 = fmaxf(fmaf(-2.0f, tmax[mi][r], f2[row]), 0.0f);
        atomicMin(&mind2[row], __float_as_int(d2));
      }
  }
}

__global__ __launch_bounds__(256) void finalize_kernel(
    const int* __restrict__ mind2, float* __restrict__ out)
{
  const int i = blockIdx.x * 256 + threadIdx.x;
  out[i] = sqrtf(fmaxf(__int_as_float(mind2[i]), 0.0f));
}

extern "C" void kernel_launch(void* const* d_in, const int* in_sizes, int n_in,
                              void* d_out, int out_size, void* d_ws, size_t ws_size,
                              hipStream_t stream) {
  const float* f = (const float*)d_in[0];  // features  [8192,1,1,128] fp32
  const float* m = (const float*)d_in[1];  // patch_mem [1,16384,1,128] fp32

  char* ws = (char*)d_ws;
  u16*  fb    = (u16*)(ws);                                   // 2 MB
  u16*  mb    = (u16*)(ws + (2u << 20));                      // 4 MB
  float* f2   = (float*)(ws + (2u << 20) + (4u << 20));       // 32 KB
  float* mh   = (float*)(ws + (2u << 20) + (4u << 20) + (32u << 10));  // 64 KB
  int*  mind2 = (int*)(ws + (2u << 20) + (4u << 20) + (96u << 10));    // 32 KB

  hipLaunchKernelGGL(prep_kernel, dim3((N_ROWS + M_ROWS) / 4), dim3(256), 0, stream,
                     f, m, fb, mb, f2, mh, mind2);
  hipLaunchKernelGGL(gemm_min_kernel, dim3(MSPLIT, N_ROWS / 256), dim3(256), 0, stream,
                     fb, mb, f2, mh, mind2);
  hipLaunchKernelGGL(finalize_kernel, dim3(N_ROWS / 256), dim3(256), 0, stream,
                     mind2, (float*)d_out);
}

// Round 12
// 55.664 us; speedup vs baseline: 1.6400x; 1.5076x over previous
//
#include <hip/hip_runtime.h>
#include <hip/hip_bf16.h>
#include <stdint.h>

#define N_ROWS 8192
#define M_ROWS 16384
#define CDIM 128
#define MSPLIT 16      // B slices
#define SLICE_ROWS 1024
#define NT 32          // 32-row B tiles per slice

typedef unsigned short u16;
typedef __attribute__((ext_vector_type(8))) short bf16x8;
typedef __attribute__((ext_vector_type(16))) float f32x16;

static __device__ __forceinline__ u16 f2bf(float x) {
  union { float f; uint32_t u; } v; v.f = x;
  uint32_t u = v.u;
  uint32_t r = u + 0x7FFFu + ((u >> 16) & 1u);  // RTNE
  return (u16)(r >> 16);
}
static __device__ __forceinline__ float bf2f(u16 b) {
  union { uint32_t u; float f; } v; v.u = ((uint32_t)b) << 16;
  return v.f;
}

// One wave per row. fp32 -> bf16, row sum-of-squares (fp32 accum), and
// FRAGMENT-ORDER store: the 16B chunk for (tile=row>>5, ks, lane') lands at
// ((tile*8+ks)*64 + lane')*16B, lane' = l5*32 + (row&31). Lane handles u16s
// u=lane*2, u+1 of its row: ks=u>>4, l5'=(u>>3)&1, j=u&7. This makes every
// gemm fragment load a single coalesced base+lane*16 transaction (round-11
// post-mortem: row-strided fragment loads shattered into 32 segments/instr).
__global__ __launch_bounds__(256) void prep_kernel(
    const float* __restrict__ f, const float* __restrict__ m,
    u16* __restrict__ fb, u16* __restrict__ mb,
    float* __restrict__ f2, float* __restrict__ mh, int* __restrict__ mind2)
{
  const int row = blockIdx.x * 4 + (threadIdx.x >> 6);
  const int lane = threadIdx.x & 63;
  const bool isF = row < N_ROWS;
  const int r = isF ? row : row - N_ROWS;
  const float* src = (isF ? f : m) + (size_t)r * CDIM;
  float2 v = *(const float2*)(src + lane * 2);
  u16 b0 = f2bf(v.x), b1 = f2bf(v.y);
  float x0 = bf2f(b0), x1 = bf2f(b1);
  float s = x0 * x0 + x1 * x1;
#pragma unroll
  for (int mask = 1; mask < 64; mask <<= 1)
    s += __shfl_xor(s, mask, 64);

  const int t = r >> 5, lr = r & 31;
  const int ks = lane >> 3;
  const int l5p = (lane >> 2) & 1;
  const int j = (lane & 3) * 2;
  u16* dst = (isF ? fb : mb)
             + ((size_t)(t * 8 + ks) * 64 + l5p * 32 + lr) * 8 + j;
  dst[0] = b0; dst[1] = b1;
  if (lane == 0) {
    if (isF) { f2[r] = s; mind2[r] = 0x7F7FFFFF; }  // +FLT_MAX bits
    else     { mh[r] = -0.5f * s; }
  }
}

// ZERO-LDS, ZERO-BARRIER register GEMM on fragment-order inputs.
// Block = 4 free-running waves; wave tile 64A x 32B, mfma_f32_32x32x16_bf16.
// af: 16 coalesced 16B loads (64 VGPR, once). B streams global->VGPR as
// 8 x 1KB coalesced loads per 32-row tile, double-buffered one tile ahead;
// dual accumulators overlap the fold-VALU of tile t with MFMA of t+1.
// acc seeded with mh=-m2/2 (C/D col==l31 for all regs), so
// min d2 = f2 - 2*max(acc). All 4 waves share the B tile stream (L1).
// grid (16 msplit, 32 abase) = 512 blocks = 2/CU; msplit%8 pins the XCD
// (B' slice 2x256KB + A' reuse, L2-resident).
__global__ __launch_bounds__(256, 2) void gemm_min_kernel(
    const u16* __restrict__ fb, const u16* __restrict__ mb,
    const float* __restrict__ f2, const float* __restrict__ mh,
    int* __restrict__ mind2)
{
  const int tid = threadIdx.x;
  const int lane = tid & 63;
  const int w = tid >> 6;          // 0..3 : 64-row A group
  const int l31 = lane & 31;
  const int l5 = lane >> 5;        // 0/1 : k-half
  const int abase = blockIdx.y * 256;
  const size_t mslice = (size_t)blockIdx.x * SLICE_ROWS;

  // A fragments (fragment-order, coalesced): ta = abase/32 + w*2 + mi.
  bf16x8 af[2][8];  // [mi][ks]
#pragma unroll
  for (int mi = 0; mi < 2; ++mi) {
    const int ta = (abase >> 5) + w * 2 + mi;
#pragma unroll
    for (int ks = 0; ks < 8; ++ks)
      af[mi][ks] = *(const bf16x8*)&fb[((size_t)(ta * 8 + ks) * 64 + lane) * 8];
  }

  // B fragment stream base: tile tb = mslice/32 + t.
  const u16* bbase = mb + ((size_t)(mslice >> 5) * 8 * 64) * 8;
  const float* mhp = mh + mslice + l31;

  bf16x8 bgA[8], bgB[8];
  float mhA, mhB;
#pragma unroll
  for (int ks = 0; ks < 8; ++ks)
    bgA[ks] = *(const bf16x8*)&bbase[((size_t)ks * 64 + lane) * 8];  // tile 0
  mhA = mhp[0];

  float tmax[2][16];
#pragma unroll
  for (int mi = 0; mi < 2; ++mi)
#pragma unroll
    for (int r = 0; r < 16; ++r) tmax[mi][r] = -3.0e38f;

  f32x16 accA[2], accB[2];
#pragma unroll
  for (int mi = 0; mi < 2; ++mi)
#pragma unroll
    for (int r = 0; r < 16; ++r) accB[mi][r] = -3.0e38f;  // first fold no-op

  for (int t = 0; t < NT; t += 2) {
    // Prefetch tile t+1 into bgB (coalesced 1KB loads).
    {
      const u16* bp1 = bbase + (size_t)(t + 1) * (8 * 64 * 8);
#pragma unroll
      for (int ks = 0; ks < 8; ++ks)
        bgB[ks] = *(const bf16x8*)&bp1[((size_t)ks * 64 + lane) * 8];
      mhB = mhp[(t + 1) * 32];
    }
    // Seed accA with -m2/2, compute tile t; fold tile t-1 (accB) meanwhile.
#pragma unroll
    for (int mi = 0; mi < 2; ++mi)
#pragma unroll
      for (int r = 0; r < 16; ++r) accA[mi][r] = mhA;
#pragma unroll
    for (int ks = 0; ks < 8; ++ks)
#pragma unroll
      for (int mi = 0; mi < 2; ++mi)
        accA[mi] = __builtin_amdgcn_mfma_f32_32x32x16_bf16(
            af[mi][ks], bgA[ks], accA[mi], 0, 0, 0);
#pragma unroll
    for (int mi = 0; mi < 2; ++mi)
#pragma unroll
      for (int r = 0; r < 16; ++r)
        tmax[mi][r] = fmaxf(tmax[mi][r], accB[mi][r]);

    // Prefetch tile t+2 into bgA (wraps harmlessly at the end).
    {
      const u16* bp2 = bbase + (size_t)((t + 2) & (NT - 1)) * (8 * 64 * 8);
#pragma unroll
      for (int ks = 0; ks < 8; ++ks)
        bgA[ks] = *(const bf16x8*)&bp2[((size_t)ks * 64 + lane) * 8];
      mhA = mhp[((t + 2) & (NT - 1)) * 32];
    }
    // Seed accB, compute tile t+1; fold tile t (accA) meanwhile.
#pragma unroll
    for (int mi = 0; mi < 2; ++mi)
#pragma unroll
      for (int r = 0; r < 16; ++r) accB[mi][r] = mhB;
#pragma unroll
    for (int ks = 0; ks < 8; ++ks)
#pragma unroll
      for (int mi = 0; mi < 2; ++mi)
        accB[mi] = __builtin_amdgcn_mfma_f32_32x32x16_bf16(
            af[mi][ks], bgB[ks], accB[mi], 0, 0, 0);
#pragma unroll
    for (int mi = 0; mi < 2; ++mi)
#pragma unroll
      for (int r = 0; r < 16; ++r)
        tmax[mi][r] = fmaxf(tmax[mi][r], accA[mi][r]);
  }
  // Fold the last odd tile (accB of t=NT-1).
#pragma unroll
  for (int mi = 0; mi < 2; ++mi)
#pragma unroll
    for (int r = 0; r < 16; ++r)
      tmax[mi][r] = fmaxf(tmax[mi][r], accB[mi][r]);

  // Reduce across the 32 lanes (l31) holding a row's B-columns.
#pragma unroll
  for (int mi = 0; mi < 2; ++mi)
#pragma unroll
    for (int r = 0; r < 16; ++r) {
      float tv = tmax[mi][r];
      tv = fmaxf(tv, __shfl_xor(tv, 1, 64));
      tv = fmaxf(tv, __shfl_xor(tv, 2, 64));
      tv = fmaxf(tv, __shfl_xor(tv, 4, 64));
      tv = fmaxf(tv, __shfl_xor(tv, 8, 64));
      tv = fmaxf(tv, __shfl_xor(tv, 16, 64));
      tmax[mi][r] = tv;
    }
  if (l31 == 0) {  // lanes 0 and 32 (l5 = 0/1)
#pragma unroll
    for (int mi = 0; mi < 2; ++mi)
#pragma unroll
      for (int r = 0; r < 16; ++r) {
        // C/D: row = (r&3) + 8*(r>>2) + 4*l5 within the 32-row fragment.
        const int row = abase + w * 64 + mi * 32
                        + (r & 3) + 8 * (r >> 2) + 4 * l5;
        const float d2 = fmaxf(fmaf(-2.0f, tmax[mi][r], f2[row]), 0.0f);
        atomicMin(&mind2[row], __float_as_int(d2));
      }
  }
}

__global__ __launch_bounds__(256) void finalize_kernel(
    const int* __restrict__ mind2, float* __restrict__ out)
{
  const int i = blockIdx.x * 256 + threadIdx.x;
  out[i] = sqrtf(fmaxf(__int_as_float(mind2[i]), 0.0f));
}

extern "C" void kernel_launch(void* const* d_in, const int* in_sizes, int n_in,
                              void* d_out, int out_size, void* d_ws, size_t ws_size,
                              hipStream_t stream) {
  const float* f = (const float*)d_in[0];  // features  [8192,1,1,128] fp32
  const float* m = (const float*)d_in[1];  // patch_mem [1,16384,1,128] fp32

  char* ws = (char*)d_ws;
  u16*  fb    = (u16*)(ws);                                   // 2 MB (fragment order)
  u16*  mb    = (u16*)(ws + (2u << 20));                      // 4 MB (fragment order)
  float* f2   = (float*)(ws + (2u << 20) + (4u << 20));       // 32 KB
  float* mh   = (float*)(ws + (2u << 20) + (4u << 20) + (32u << 10));  // 64 KB
  int*  mind2 = (int*)(ws + (2u << 20) + (4u << 20) + (96u << 10));    // 32 KB

  hipLaunchKernelGGL(prep_kernel, dim3((N_ROWS + M_ROWS) / 4), dim3(256), 0, stream,
                     f, m, fb, mb, f2, mh, mind2);
  hipLaunchKernelGGL(gemm_min_kernel, dim3(MSPLIT, N_ROWS / 256), dim3(256), 0, stream,
                     fb, mb, f2, mh, mind2);
  hipLaunchKernelGGL(finalize_kernel, dim3(N_ROWS / 256), dim3(256), 0, stream,
                     mind2, (float*)d_out);
}